// Round 5
// baseline (740.374 us; speedup 1.0000x reference)
//
#include <hip/hip_runtime.h>
#include <math.h>

#define V96 (96*96*96)
#define NDIVBLK 3350   // ceil(95^3/256)
#define NMEDBLK 3456   // 3*48*24

#define SENTINEL 3.0e38f

// ---------- helpers ----------

__device__ __forceinline__ int reflect_idx(int t, int n) {
  if (t < 0) t = -t;
  if (t >= n) t = 2 * n - 2 - t;
  return t;
}

__device__ __forceinline__ void cswap(float& a, float& b) {
  float lo = fminf(a, b);
  float hi = fmaxf(a, b);
  a = lo;
  b = hi;
}

// Batcher odd-even mergesort on v[0..N), N power of 2. Fully unrolled.
template <int N>
__device__ __forceinline__ void sortn(float* v) {
#pragma unroll
  for (int p = 1; p < N; p <<= 1) {
#pragma unroll
    for (int k = p; k >= 1; k >>= 1) {
#pragma unroll
      for (int j = k % p; j <= N - 1 - k; j += 2 * k) {
#pragma unroll
        for (int i = 0; i < k; i++) {
          if (i + j + k <= N - 1) {
            if ((i + j) / (2 * p) == (i + j + k) / (2 * p)) {
              cswap(v[i + j], v[i + j + k]);
            }
          }
        }
      }
    }
  }
}

// 256-thread block: reduce val across block; result valid on tid 0.
__device__ __forceinline__ double block_reduce_sum(double val, double* sh) {
  int tid = threadIdx.x + threadIdx.y * blockDim.x +
            threadIdx.z * blockDim.x * blockDim.y;
  int lane = tid & 63;
  int wv = tid >> 6;
#pragma unroll
  for (int off = 32; off > 0; off >>= 1) val += __shfl_down(val, off, 64);
  if (lane == 0) sh[wv] = val;
  __syncthreads();
  double r = 0.0;
  if (tid == 0) {
#pragma unroll
    for (int i = 0; i < 4; i++) r += sh[i];
  }
  return r;
}

// ---------- stage 1: masked fields ----------

__global__ __launch_bounds__(256) void prep_mask_kernel(
    const float* __restrict__ pred_b, const float* __restrict__ targets,
    float* __restrict__ bxm, float* __restrict__ bym) {
  int i = blockIdx.x * 256 + threadIdx.x;
  if (i >= V96) return;
  float bxp = pred_b[i];
  float byp = pred_b[V96 + i];
  float bxt = targets[i];
  float byt = targets[V96 + i];
  float m = (bxp * bxt + byp * byt > 0.0f) ? 1.0f : -1.0f;
  bxm[i] = bxt * m;
  bym[i] = byt * m;
}

// ---------- stage 2: div-c flux reduction (95^3 cells) ----------

__global__ __launch_bounds__(256) void div_kernel(
    const float* __restrict__ bx, const float* __restrict__ by,
    const float* __restrict__ bz, const float* __restrict__ z,
    double* __restrict__ part_sum, double* __restrict__ part_sq) {
  __shared__ double sh1[4];
  __shared__ double sh2[4];
  const int N = 95 * 95 * 95;
  int idx = blockIdx.x * 256 + threadIdx.x;
  double fs = 0.0, fq = 0.0;
  if (idx < N) {
    int w = idx % 95;
    int t = idx / 95;
    int h = t % 95;
    int d = t / 95;
    int o = (d * 96 + h) * 96 + w;
#define LD8(A, p)                                                             \
  float A##000 = p[o], A##001 = p[o + 1], A##010 = p[o + 96],                 \
        A##011 = p[o + 97], A##100 = p[o + 9216], A##101 = p[o + 9217],       \
        A##110 = p[o + 9312], A##111 = p[o + 9313];
    LD8(bxv, bx)
    LD8(byv, by)
    LD8(bzv, bz)
    LD8(zv, z)
#undef LD8
    float az1 = fabsf(zv001 - zv000);
    float az2 = fabsf(zv011 - zv010);
    float az3 = fabsf(zv101 - zv100);
    float az4 = fabsf(zv111 - zv110);
    const float c6 = 1.0f / 6.0f;
    const float c3 = 1.0f / 3.0f;
    float flux =
        0.25f * (bxv100 + bxv110 + bxv101 + bxv111) * 0.5f * (az3 + az4) -
        0.25f * (bxv000 + bxv010 + bxv001 + bxv011) * 0.5f * (az1 + az2) +
        0.25f * (byv010 + byv110 + byv011 + byv111) * 0.5f * (az2 + az4) -
        0.25f * (byv000 + byv100 + byv001 + byv101) * 0.5f * (az1 + az3) +
        0.5f * ((bzv001 + bzv101 + bzv111) + (bzv001 + bzv111 + bzv011)) * c3 -
        0.5f * ((bzv000 + bzv100 + bzv110) + (bzv000 + bzv110 + bzv010)) * c3 +
        (bxv001 + bxv101 + bxv111) * (zv001 - zv101) * c6 +
        (bxv001 + bxv011 + bxv111) * (zv011 - zv111) * c6 +
        (byv001 + byv101 + byv111) * (zv101 - zv111) * c6 +
        (byv001 + byv011 + byv111) * (zv001 - zv011) * c6 -
        ((bxv000 + bxv100 + bxv110) * (zv000 - zv100) * c6 +
         (bxv000 + bxv010 + bxv110) * (zv010 - zv110) * c6 +
         (byv000 + byv100 + byv110) * (zv100 - zv110) * c6 +
         (byv000 + byv010 + byv110) * (zv000 - zv010) * c6);
    float sbx = bxv000 + bxv001 + bxv010 + bxv011 + bxv100 + bxv101 + bxv110 +
                bxv111;
    float sby = byv000 + byv001 + byv010 + byv011 + byv100 + byv101 + byv110 +
                byv111;
    float sbz = bzv000 + bzv001 + bzv010 + bzv011 + bzv100 + bzv101 + bzv110 +
                bzv111;
    float ave = 0.015625f * (sbx * sbx + sby * sby + sbz * sbz) + 1e-8f;
    float res = flux * flux;
    float flx1 = res * res / ave;
    fs = (double)flx1;
    fq = (double)flx1 * (double)flx1;
  }
  double bs = block_reduce_sum(fs, sh1);
  double bq = block_reduce_sum(fq, sh2);
  if (threadIdx.x == 0) {
    part_sum[blockIdx.x] = bs;
    part_sq[blockIdx.x] = bq;
  }
}

// ---------- stage 3: median filter + sum((x-med)^2) ----------
// Block (32,2,4) -> output tile 32x2x4. Tile [8][6][36]: conflict-free.
// LIVENESS-CAPPED median: phase A sorts window elems 0..63 and parks the
// needed ranks 0..62 in LDS (Asr[63][256], lane->bank 2-way = free); a
// barrier fences the scheduler; phase B sorts elems 64..124 (+3 sentinels);
// the rank-62-of-union select streams A back from LDS. Peak reg liveness
// ~70 floats -> no AGPR spill (R2-R4 all spilled: 128-float front, issued
// ~5500 instr/wave at VGPR_Count=124 regardless of launch_bounds).
// MODE 0: plain field f (dims D,H,W)
// MODE 1: jx on the fly (96,95,95)   MODE 2: jy (95,96,95)   MODE 3: jz (95,95,96)

template <int MODE>
__global__ __launch_bounds__(256, 2) void med_kernel(
    const float* __restrict__ f, const float* __restrict__ bxm,
    const float* __restrict__ bym, const float* __restrict__ bzp, int D, int H,
    int W, double* __restrict__ part) {
  __shared__ float tile[8][6][36];
  __shared__ float Asr[63][256];
  __shared__ double sh[4];
  const int w0 = blockIdx.x * 32;
  const int h0 = blockIdx.y * 2;
  const int d0 = blockIdx.z * 4;
  const int tx = threadIdx.x;  // 0..31
  const int ty = threadIdx.y;  // 0..1
  const int tz = threadIdx.z;  // 0..3
  const int tid = tx + 32 * ty + 64 * tz;

  for (int il = tid; il < 8 * 6 * 36; il += 256) {
    int lw = il % 36;
    int lh = (il / 36) % 6;
    int ld = il / 216;
    int gw = reflect_idx(w0 + lw - 2, W);
    int gh = reflect_idx(h0 + lh - 2, H);
    int gd = reflect_idx(d0 + ld - 2, D);
    float val;
    if (MODE == 0) {
      val = f[(gd * H + gh) * W + gw];
    } else {
      int o = (gd * 96 + gh) * 96 + gw;
      if (MODE == 1) {
        val = 0.5f * ((bzp[o] - bzp[o + 96] + bzp[o + 1] - bzp[o + 97]) -
                      (bym[o] - bym[o + 1] + bym[o + 96] - bym[o + 97]));
      } else if (MODE == 2) {
        val = 0.5f *
              ((bxm[o] - bxm[o + 1] + bxm[o + 9216] - bxm[o + 9217]) -
               (bzp[o] - bzp[o + 9216] + bzp[o + 1] - bzp[o + 9217]));
      } else {
        val = 0.5f *
              ((bym[o] - bym[o + 9216] + bym[o + 96] - bym[o + 9312]) -
               (bxm[o] - bxm[o + 96] + bxm[o + 9216] - bxm[o + 9312]));
      }
    }
    tile[ld][lh][lw] = val;
  }
  __syncthreads();

  // window element r -> (i,j,l) = (r/25, (r/5)%5, r%5)
#define TW(r) tile[tz + (r) / 25][ty + ((r) / 5) % 5][tx + (r) % 5]

  // ---- phase A: sort first 64, park ranks 0..62 in LDS ----
  {
    float A[64];
#pragma unroll
    for (int r = 0; r < 64; r++) A[r] = TW(r);
    sortn<64>(A);
#pragma unroll
    for (int i = 0; i < 63; i++) Asr[i][tid] = A[i];
  }
  __syncthreads();  // scheduler fence: keeps phase B's loads below A's death

  // ---- phase B: sort remaining 61 + 3 sentinels ----
  float B[64];
#pragma unroll
  for (int r = 64; r < 125; r++) B[r - 64] = TW(r);
  B[61] = SENTINEL;
  B[62] = SENTINEL;
  B[63] = SENTINEL;
  sortn<64>(B);

  float center = tile[tz + 2][ty + 2][tx + 2];
#undef TW

  // ---- select rank 62 (0-based) of the 128-union (125 real + 3 sentinels):
  // med = min( B[62], A[62], min_{i=1..62} max(A[i-1], B[62-i]) )
  float m0 = B[62];
  float m1 = Asr[62][tid];
  float m2 = SENTINEL;
  float m3 = SENTINEL;
#pragma unroll
  for (int i = 1; i <= 60; i += 4) {
    m0 = fminf(m0, fmaxf(Asr[i - 1][tid], B[62 - i]));
    m1 = fminf(m1, fmaxf(Asr[i][tid], B[61 - i]));
    m2 = fminf(m2, fmaxf(Asr[i + 1][tid], B[60 - i]));
    m3 = fminf(m3, fmaxf(Asr[i + 2][tid], B[59 - i]));
  }
  // i = 61, 62
  m0 = fminf(m0, fmaxf(Asr[60][tid], B[1]));
  m1 = fminf(m1, fmaxf(Asr[61][tid], B[0]));
  float m = fminf(fminf(m0, m1), fminf(m2, m3));

  float dlt = m - center;
  const int w = w0 + tx;
  const int h = h0 + ty;
  const int d = d0 + tz;
  double c = (w < W && h < H && d < D) ? (double)dlt * (double)dlt : 0.0;
  double bs = block_reduce_sum(c, sh);
  if (tid == 0) {
    part[blockIdx.x + 3 * (blockIdx.y + 48 * blockIdx.z)] = bs;
  }
}

// ---------- stage 4: reduce partials, finalize 6 scalars ----------

__global__ __launch_bounds__(256) void finalize_kernel(
    const double* __restrict__ P, float* __restrict__ out) {
  __shared__ double sh[4];
  __shared__ double res[11];
  int tid = threadIdx.x;
  for (int q = 0; q < 11; q++) {
    const double* base =
        (q < 4) ? (P + q * NDIVBLK) : (P + 4 * NDIVBLK + (q - 4) * NMEDBLK);
    int cnt = (q < 4) ? NDIVBLK : NMEDBLK;
    double s = 0.0;
    for (int i = tid; i < cnt; i += 256) s += base[i];
#pragma unroll
    for (int off = 32; off > 0; off >>= 1) s += __shfl_down(s, off, 64);
    if ((tid & 63) == 0) sh[tid >> 6] = s;
    __syncthreads();
    if (tid == 0) res[q] = sh[0] + sh[1] + sh[2] + sh[3];
    __syncthreads();
  }
  if (tid == 0) {
    const double Nd = 95.0 * 95.0 * 95.0;
    const double Nj = 96.0 * 95.0 * 95.0;
    const double Nv = 96.0 * 96.0 * 96.0;
    double mp = res[0] / Nd;
    double mt = res[2] / Nd;
    out[0] = (float)mp;
    out[1] = (float)(res[1] / Nd - mp * mp);
    out[2] = (float)mt;
    out[3] = (float)(res[3] / Nd - mt * mt);
    out[4] = (float)((res[4] + res[5] + res[6]) / Nj);
    out[5] = (float)((res[7] + res[8] + res[9] + res[10]) / Nv);
  }
}

// ---------- launcher ----------

extern "C" void kernel_launch(void* const* d_in, const int* in_sizes, int n_in,
                              void* d_out, int out_size, void* d_ws,
                              size_t ws_size, hipStream_t stream) {
  (void)in_sizes;
  (void)n_in;
  (void)out_size;
  (void)ws_size;
  const float* pred_b = (const float*)d_in[0];
  const float* pred_z = (const float*)d_in[1];
  const float* targets = (const float*)d_in[2];
  float* out = (float*)d_out;

  double* P = (double*)d_ws;                     // 4*NDIVBLK + 7*NMEDBLK doubles
  size_t pdoubles = 4 * NDIVBLK + 7 * NMEDBLK;
  float* bxm = (float*)(P + pdoubles);
  float* bym = bxm + V96;

  const float* bzt = targets + 2 * V96;
  const float* bzp = pred_b + 2 * V96;

  prep_mask_kernel<<<dim3((V96 + 255) / 256), dim3(256), 0, stream>>>(
      pred_b, targets, bxm, bym);

  div_kernel<<<dim3(NDIVBLK), dim3(256), 0, stream>>>(
      pred_b, pred_b + V96, bzt, pred_z, P + 0 * NDIVBLK, P + 1 * NDIVBLK);
  div_kernel<<<dim3(NDIVBLK), dim3(256), 0, stream>>>(
      bxm, bym, bzt, pred_z, P + 2 * NDIVBLK, P + 3 * NDIVBLK);

  double* M = P + 4 * NDIVBLK;
  dim3 blk(32, 2, 4);
  dim3 grd(3, 48, 24);
  med_kernel<1><<<grd, blk, 0, stream>>>(nullptr, bxm, bym, bzp, 96, 95, 95,
                                         M + 0 * NMEDBLK);
  med_kernel<2><<<grd, blk, 0, stream>>>(nullptr, bxm, bym, bzp, 95, 96, 95,
                                         M + 1 * NMEDBLK);
  med_kernel<3><<<grd, blk, 0, stream>>>(nullptr, bxm, bym, bzp, 95, 95, 96,
                                         M + 2 * NMEDBLK);
  med_kernel<0><<<grd, blk, 0, stream>>>(bxm, bxm, bym, bzp, 96, 96, 96,
                                         M + 3 * NMEDBLK);
  med_kernel<0><<<grd, blk, 0, stream>>>(bym, bxm, bym, bzp, 96, 96, 96,
                                         M + 4 * NMEDBLK);
  med_kernel<0><<<grd, blk, 0, stream>>>(pred_b, bxm, bym, bzp, 96, 96, 96,
                                         M + 5 * NMEDBLK);
  med_kernel<0><<<grd, blk, 0, stream>>>(pred_b + V96, bxm, bym, bzp, 96, 96,
                                         96, M + 6 * NMEDBLK);

  finalize_kernel<<<1, 256, 0, stream>>>(P, out);
}

// Round 6
// 708.178 us; speedup vs baseline: 1.0455x; 1.0455x over previous
//
#include <hip/hip_runtime.h>
#include <math.h>

#define V96 (96*96*96)
#define NDIVBLK 3350   // ceil(95^3/256)
#define NMEDBLK 3456   // 3*48*24

#define KSENT 0x7FFFFFFF  // int-key sentinel, > key(+inf)=0x7F800000

// ---------- helpers ----------

__device__ __forceinline__ int reflect_idx(int t, int n) {
  if (t < 0) t = -t;
  if (t >= n) t = 2 * n - 2 - t;
  return t;
}

// Monotone float<->signed-int key transform (involution):
// key(f) = b ^ ((b>>31) & 0x7FFFFFFF), b = bits(f). Preserves total order
// (ex-NaN). Whole sort network runs in v_min_i32/v_max_i32 — no IEEE
// canonicalization tax that float min/max chains pay without fast-math.
__device__ __forceinline__ int fkey(float f) {
  int b = __float_as_int(f);
  return b ^ ((b >> 31) & 0x7FFFFFFF);
}
__device__ __forceinline__ float funkey(int k) {
  return __int_as_float(k ^ ((k >> 31) & 0x7FFFFFFF));
}

__device__ __forceinline__ void cswap(int& a, int& b) {
  int lo = min(a, b);
  int hi = max(a, b);
  a = lo;
  b = hi;
}

// Batcher odd-even mergesort on v[0..N), N power of 2. Fully unrolled.
template <int N>
__device__ __forceinline__ void sortn(int* v) {
#pragma unroll
  for (int p = 1; p < N; p <<= 1) {
#pragma unroll
    for (int k = p; k >= 1; k >>= 1) {
#pragma unroll
      for (int j = k % p; j <= N - 1 - k; j += 2 * k) {
#pragma unroll
        for (int i = 0; i < k; i++) {
          if (i + j + k <= N - 1) {
            if ((i + j) / (2 * p) == (i + j + k) / (2 * p)) {
              cswap(v[i + j], v[i + j + k]);
            }
          }
        }
      }
    }
  }
}

// 256-thread block: reduce val across block; result valid on tid 0.
__device__ __forceinline__ double block_reduce_sum(double val, double* sh) {
  int tid = threadIdx.x + threadIdx.y * blockDim.x +
            threadIdx.z * blockDim.x * blockDim.y;
  int lane = tid & 63;
  int wv = tid >> 6;
#pragma unroll
  for (int off = 32; off > 0; off >>= 1) val += __shfl_down(val, off, 64);
  if (lane == 0) sh[wv] = val;
  __syncthreads();
  double r = 0.0;
  if (tid == 0) {
#pragma unroll
    for (int i = 0; i < 4; i++) r += sh[i];
  }
  return r;
}

// ---------- stage 1: masked fields ----------

__global__ __launch_bounds__(256) void prep_mask_kernel(
    const float* __restrict__ pred_b, const float* __restrict__ targets,
    float* __restrict__ bxm, float* __restrict__ bym) {
  int i = blockIdx.x * 256 + threadIdx.x;
  if (i >= V96) return;
  float bxp = pred_b[i];
  float byp = pred_b[V96 + i];
  float bxt = targets[i];
  float byt = targets[V96 + i];
  float m = (bxp * bxt + byp * byt > 0.0f) ? 1.0f : -1.0f;
  bxm[i] = bxt * m;
  bym[i] = byt * m;
}

// ---------- stage 2: div-c flux reduction (95^3 cells) ----------

__global__ __launch_bounds__(256) void div_kernel(
    const float* __restrict__ bx, const float* __restrict__ by,
    const float* __restrict__ bz, const float* __restrict__ z,
    double* __restrict__ part_sum, double* __restrict__ part_sq) {
  __shared__ double sh1[4];
  __shared__ double sh2[4];
  const int N = 95 * 95 * 95;
  int idx = blockIdx.x * 256 + threadIdx.x;
  double fs = 0.0, fq = 0.0;
  if (idx < N) {
    int w = idx % 95;
    int t = idx / 95;
    int h = t % 95;
    int d = t / 95;
    int o = (d * 96 + h) * 96 + w;
#define LD8(A, p)                                                             \
  float A##000 = p[o], A##001 = p[o + 1], A##010 = p[o + 96],                 \
        A##011 = p[o + 97], A##100 = p[o + 9216], A##101 = p[o + 9217],       \
        A##110 = p[o + 9312], A##111 = p[o + 9313];
    LD8(bxv, bx)
    LD8(byv, by)
    LD8(bzv, bz)
    LD8(zv, z)
#undef LD8
    float az1 = fabsf(zv001 - zv000);
    float az2 = fabsf(zv011 - zv010);
    float az3 = fabsf(zv101 - zv100);
    float az4 = fabsf(zv111 - zv110);
    const float c6 = 1.0f / 6.0f;
    const float c3 = 1.0f / 3.0f;
    float flux =
        0.25f * (bxv100 + bxv110 + bxv101 + bxv111) * 0.5f * (az3 + az4) -
        0.25f * (bxv000 + bxv010 + bxv001 + bxv011) * 0.5f * (az1 + az2) +
        0.25f * (byv010 + byv110 + byv011 + byv111) * 0.5f * (az2 + az4) -
        0.25f * (byv000 + byv100 + byv001 + byv101) * 0.5f * (az1 + az3) +
        0.5f * ((bzv001 + bzv101 + bzv111) + (bzv001 + bzv111 + bzv011)) * c3 -
        0.5f * ((bzv000 + bzv100 + bzv110) + (bzv000 + bzv110 + bzv010)) * c3 +
        (bxv001 + bxv101 + bxv111) * (zv001 - zv101) * c6 +
        (bxv001 + bxv011 + bxv111) * (zv011 - zv111) * c6 +
        (byv001 + byv101 + byv111) * (zv101 - zv111) * c6 +
        (byv001 + byv011 + byv111) * (zv001 - zv011) * c6 -
        ((bxv000 + bxv100 + bxv110) * (zv000 - zv100) * c6 +
         (bxv000 + bxv010 + bxv110) * (zv010 - zv110) * c6 +
         (byv000 + byv100 + byv110) * (zv100 - zv110) * c6 +
         (byv000 + byv010 + byv110) * (zv000 - zv010) * c6);
    float sbx = bxv000 + bxv001 + bxv010 + bxv011 + bxv100 + bxv101 + bxv110 +
                bxv111;
    float sby = byv000 + byv001 + byv010 + byv011 + byv100 + byv101 + byv110 +
                byv111;
    float sbz = bzv000 + bzv001 + bzv010 + bzv011 + bzv100 + bzv101 + bzv110 +
                bzv111;
    float ave = 0.015625f * (sbx * sbx + sby * sby + sbz * sbz) + 1e-8f;
    float res = flux * flux;
    float flx1 = res * res / ave;
    fs = (double)flx1;
    fq = (double)flx1 * (double)flx1;
  }
  double bs = block_reduce_sum(fs, sh1);
  double bq = block_reduce_sum(fq, sh2);
  if (threadIdx.x == 0) {
    part_sum[blockIdx.x] = bs;
    part_sq[blockIdx.x] = bq;
  }
}

// ---------- stage 3: median filter + sum((x-med)^2) ----------
// R5 structure (liveness-capped via LDS staging, no AGPR spill) with the
// whole network moved to the monotone int-key domain (v_min_i32/v_max_i32).
// MODE 0: plain field f (dims D,H,W)
// MODE 1: jx on the fly (96,95,95)   MODE 2: jy (95,96,95)   MODE 3: jz (95,95,96)

template <int MODE>
__global__ __launch_bounds__(256, 2) void med_kernel(
    const float* __restrict__ f, const float* __restrict__ bxm,
    const float* __restrict__ bym, const float* __restrict__ bzp, int D, int H,
    int W, double* __restrict__ part) {
  __shared__ int tile[8][6][36];
  __shared__ int Asr[63][256];
  __shared__ double sh[4];
  const int w0 = blockIdx.x * 32;
  const int h0 = blockIdx.y * 2;
  const int d0 = blockIdx.z * 4;
  const int tx = threadIdx.x;  // 0..31
  const int ty = threadIdx.y;  // 0..1
  const int tz = threadIdx.z;  // 0..3
  const int tid = tx + 32 * ty + 64 * tz;

  for (int il = tid; il < 8 * 6 * 36; il += 256) {
    int lw = il % 36;
    int lh = (il / 36) % 6;
    int ld = il / 216;
    int gw = reflect_idx(w0 + lw - 2, W);
    int gh = reflect_idx(h0 + lh - 2, H);
    int gd = reflect_idx(d0 + ld - 2, D);
    float val;
    if (MODE == 0) {
      val = f[(gd * H + gh) * W + gw];
    } else {
      int o = (gd * 96 + gh) * 96 + gw;
      if (MODE == 1) {
        val = 0.5f * ((bzp[o] - bzp[o + 96] + bzp[o + 1] - bzp[o + 97]) -
                      (bym[o] - bym[o + 1] + bym[o + 96] - bym[o + 97]));
      } else if (MODE == 2) {
        val = 0.5f *
              ((bxm[o] - bxm[o + 1] + bxm[o + 9216] - bxm[o + 9217]) -
               (bzp[o] - bzp[o + 9216] + bzp[o + 1] - bzp[o + 9217]));
      } else {
        val = 0.5f *
              ((bym[o] - bym[o + 9216] + bym[o + 96] - bym[o + 9312]) -
               (bxm[o] - bxm[o + 96] + bxm[o + 9216] - bxm[o + 9312]));
      }
    }
    tile[ld][lh][lw] = fkey(val);
  }
  __syncthreads();

  // window element r -> (i,j,l) = (r/25, (r/5)%5, r%5)
#define TW(r) tile[tz + (r) / 25][ty + ((r) / 5) % 5][tx + (r) % 5]

  // ---- phase A: sort first 64 keys, park ranks 0..62 in LDS ----
  {
    int A[64];
#pragma unroll
    for (int r = 0; r < 64; r++) A[r] = TW(r);
    sortn<64>(A);
#pragma unroll
    for (int i = 0; i < 63; i++) Asr[i][tid] = A[i];
  }
  __syncthreads();  // scheduler fence: keeps phase B's loads below A's death

  // ---- phase B: sort remaining 61 keys + 3 sentinels ----
  int B[64];
#pragma unroll
  for (int r = 64; r < 125; r++) B[r - 64] = TW(r);
  B[61] = KSENT;
  B[62] = KSENT;
  B[63] = KSENT;
  sortn<64>(B);

  int ckey = tile[tz + 2][ty + 2][tx + 2];
#undef TW

  // ---- select rank 62 (0-based) of the 128-union (125 real + 3 sentinels):
  // med = min( B[62], A[62], min_{i=1..62} max(A[i-1], B[62-i]) )
  int m0 = B[62];
  int m1 = Asr[62][tid];
  int m2 = KSENT;
  int m3 = KSENT;
#pragma unroll
  for (int i = 1; i <= 60; i += 4) {
    m0 = min(m0, max(Asr[i - 1][tid], B[62 - i]));
    m1 = min(m1, max(Asr[i][tid], B[61 - i]));
    m2 = min(m2, max(Asr[i + 1][tid], B[60 - i]));
    m3 = min(m3, max(Asr[i + 2][tid], B[59 - i]));
  }
  // i = 61, 62
  m0 = min(m0, max(Asr[60][tid], B[1]));
  m1 = min(m1, max(Asr[61][tid], B[0]));
  int mk = min(min(m0, m1), min(m2, m3));

  float dlt = funkey(mk) - funkey(ckey);
  const int w = w0 + tx;
  const int h = h0 + ty;
  const int d = d0 + tz;
  double c = (w < W && h < H && d < D) ? (double)dlt * (double)dlt : 0.0;
  double bs = block_reduce_sum(c, sh);
  if (tid == 0) {
    part[blockIdx.x + 3 * (blockIdx.y + 48 * blockIdx.z)] = bs;
  }
}

// ---------- stage 4: reduce partials, finalize 6 scalars ----------

__global__ __launch_bounds__(256) void finalize_kernel(
    const double* __restrict__ P, float* __restrict__ out) {
  __shared__ double sh[4];
  __shared__ double res[11];
  int tid = threadIdx.x;
  for (int q = 0; q < 11; q++) {
    const double* base =
        (q < 4) ? (P + q * NDIVBLK) : (P + 4 * NDIVBLK + (q - 4) * NMEDBLK);
    int cnt = (q < 4) ? NDIVBLK : NMEDBLK;
    double s = 0.0;
    for (int i = tid; i < cnt; i += 256) s += base[i];
#pragma unroll
    for (int off = 32; off > 0; off >>= 1) s += __shfl_down(s, off, 64);
    if ((tid & 63) == 0) sh[tid >> 6] = s;
    __syncthreads();
    if (tid == 0) res[q] = sh[0] + sh[1] + sh[2] + sh[3];
    __syncthreads();
  }
  if (tid == 0) {
    const double Nd = 95.0 * 95.0 * 95.0;
    const double Nj = 96.0 * 95.0 * 95.0;
    const double Nv = 96.0 * 96.0 * 96.0;
    double mp = res[0] / Nd;
    double mt = res[2] / Nd;
    out[0] = (float)mp;
    out[1] = (float)(res[1] / Nd - mp * mp);
    out[2] = (float)mt;
    out[3] = (float)(res[3] / Nd - mt * mt);
    out[4] = (float)((res[4] + res[5] + res[6]) / Nj);
    out[5] = (float)((res[7] + res[8] + res[9] + res[10]) / Nv);
  }
}

// ---------- launcher ----------

extern "C" void kernel_launch(void* const* d_in, const int* in_sizes, int n_in,
                              void* d_out, int out_size, void* d_ws,
                              size_t ws_size, hipStream_t stream) {
  (void)in_sizes;
  (void)n_in;
  (void)out_size;
  (void)ws_size;
  const float* pred_b = (const float*)d_in[0];
  const float* pred_z = (const float*)d_in[1];
  const float* targets = (const float*)d_in[2];
  float* out = (float*)d_out;

  double* P = (double*)d_ws;                     // 4*NDIVBLK + 7*NMEDBLK doubles
  size_t pdoubles = 4 * NDIVBLK + 7 * NMEDBLK;
  float* bxm = (float*)(P + pdoubles);
  float* bym = bxm + V96;

  const float* bzt = targets + 2 * V96;
  const float* bzp = pred_b + 2 * V96;

  prep_mask_kernel<<<dim3((V96 + 255) / 256), dim3(256), 0, stream>>>(
      pred_b, targets, bxm, bym);

  div_kernel<<<dim3(NDIVBLK), dim3(256), 0, stream>>>(
      pred_b, pred_b + V96, bzt, pred_z, P + 0 * NDIVBLK, P + 1 * NDIVBLK);
  div_kernel<<<dim3(NDIVBLK), dim3(256), 0, stream>>>(
      bxm, bym, bzt, pred_z, P + 2 * NDIVBLK, P + 3 * NDIVBLK);

  double* M = P + 4 * NDIVBLK;
  dim3 blk(32, 2, 4);
  dim3 grd(3, 48, 24);
  med_kernel<1><<<grd, blk, 0, stream>>>(nullptr, bxm, bym, bzp, 96, 95, 95,
                                         M + 0 * NMEDBLK);
  med_kernel<2><<<grd, blk, 0, stream>>>(nullptr, bxm, bym, bzp, 95, 96, 95,
                                         M + 1 * NMEDBLK);
  med_kernel<3><<<grd, blk, 0, stream>>>(nullptr, bxm, bym, bzp, 95, 95, 96,
                                         M + 2 * NMEDBLK);
  med_kernel<0><<<grd, blk, 0, stream>>>(bxm, bxm, bym, bzp, 96, 96, 96,
                                         M + 3 * NMEDBLK);
  med_kernel<0><<<grd, blk, 0, stream>>>(bym, bxm, bym, bzp, 96, 96, 96,
                                         M + 4 * NMEDBLK);
  med_kernel<0><<<grd, blk, 0, stream>>>(pred_b, bxm, bym, bzp, 96, 96, 96,
                                         M + 5 * NMEDBLK);
  med_kernel<0><<<grd, blk, 0, stream>>>(pred_b + V96, bxm, bym, bzp, 96, 96,
                                         96, M + 6 * NMEDBLK);

  finalize_kernel<<<1, 256, 0, stream>>>(P, out);
}

// Round 7
// 607.376 us; speedup vs baseline: 1.2190x; 1.1660x over previous
//
#include <hip/hip_runtime.h>
#include <math.h>

#define V96 (96*96*96)
#define NDIVBLK 3350   // ceil(95^3/256)
#define NMEDBLK 3456   // 3*48*24

#define KSENT 0x7FFFFFFF  // int-key sentinel, > key(+inf)=0x7F800000

// ---------- helpers ----------

__device__ __forceinline__ int reflect_idx(int t, int n) {
  if (t < 0) t = -t;
  if (t >= n) t = 2 * n - 2 - t;
  return t;
}

// Monotone float<->signed-int key transform (involution).
__device__ __forceinline__ int fkey(float f) {
  int b = __float_as_int(f);
  return b ^ ((b >> 31) & 0x7FFFFFFF);
}
__device__ __forceinline__ float funkey(int k) {
  return __int_as_float(k ^ ((k >> 31) & 0x7FFFFFFF));
}

__device__ __forceinline__ void cswap(int& a, int& b) {
  int lo = min(a, b);
  int hi = max(a, b);
  a = lo;
  b = hi;
}

// Batcher odd-even mergesort on v[0..N), N power of 2. Fully unrolled.
template <int N>
__device__ __forceinline__ void sortn(int* v) {
#pragma unroll
  for (int p = 1; p < N; p <<= 1) {
#pragma unroll
    for (int k = p; k >= 1; k >>= 1) {
#pragma unroll
      for (int j = k % p; j <= N - 1 - k; j += 2 * k) {
#pragma unroll
        for (int i = 0; i < k; i++) {
          if (i + j + k <= N - 1) {
            if ((i + j) / (2 * p) == (i + j + k) / (2 * p)) {
              cswap(v[i + j], v[i + j + k]);
            }
          }
        }
      }
    }
  }
}

// 256-thread block: reduce val across block; result valid on tid 0.
__device__ __forceinline__ double block_reduce_sum(double val, double* sh) {
  int tid = threadIdx.x + threadIdx.y * blockDim.x +
            threadIdx.z * blockDim.x * blockDim.y;
  int lane = tid & 63;
  int wv = tid >> 6;
#pragma unroll
  for (int off = 32; off > 0; off >>= 1) val += __shfl_down(val, off, 64);
  if (lane == 0) sh[wv] = val;
  __syncthreads();
  double r = 0.0;
  if (tid == 0) {
#pragma unroll
    for (int i = 0; i < 4; i++) r += sh[i];
  }
  return r;
}

// ---------- stage 1: masked fields ----------

__global__ __launch_bounds__(256) void prep_mask_kernel(
    const float* __restrict__ pred_b, const float* __restrict__ targets,
    float* __restrict__ bxm, float* __restrict__ bym) {
  int i = blockIdx.x * 256 + threadIdx.x;
  if (i >= V96) return;
  float bxp = pred_b[i];
  float byp = pred_b[V96 + i];
  float bxt = targets[i];
  float byt = targets[V96 + i];
  float m = (bxp * bxt + byp * byt > 0.0f) ? 1.0f : -1.0f;
  bxm[i] = bxt * m;
  bym[i] = byt * m;
}

// ---------- stage 2: div-c flux reduction (95^3 cells) ----------

__global__ __launch_bounds__(256) void div_kernel(
    const float* __restrict__ bx, const float* __restrict__ by,
    const float* __restrict__ bz, const float* __restrict__ z,
    double* __restrict__ part_sum, double* __restrict__ part_sq) {
  __shared__ double sh1[4];
  __shared__ double sh2[4];
  const int N = 95 * 95 * 95;
  int idx = blockIdx.x * 256 + threadIdx.x;
  double fs = 0.0, fq = 0.0;
  if (idx < N) {
    int w = idx % 95;
    int t = idx / 95;
    int h = t % 95;
    int d = t / 95;
    int o = (d * 96 + h) * 96 + w;
#define LD8(A, p)                                                             \
  float A##000 = p[o], A##001 = p[o + 1], A##010 = p[o + 96],                 \
        A##011 = p[o + 97], A##100 = p[o + 9216], A##101 = p[o + 9217],       \
        A##110 = p[o + 9312], A##111 = p[o + 9313];
    LD8(bxv, bx)
    LD8(byv, by)
    LD8(bzv, bz)
    LD8(zv, z)
#undef LD8
    float az1 = fabsf(zv001 - zv000);
    float az2 = fabsf(zv011 - zv010);
    float az3 = fabsf(zv101 - zv100);
    float az4 = fabsf(zv111 - zv110);
    const float c6 = 1.0f / 6.0f;
    const float c3 = 1.0f / 3.0f;
    float flux =
        0.25f * (bxv100 + bxv110 + bxv101 + bxv111) * 0.5f * (az3 + az4) -
        0.25f * (bxv000 + bxv010 + bxv001 + bxv011) * 0.5f * (az1 + az2) +
        0.25f * (byv010 + byv110 + byv011 + byv111) * 0.5f * (az2 + az4) -
        0.25f * (byv000 + byv100 + byv001 + byv101) * 0.5f * (az1 + az3) +
        0.5f * ((bzv001 + bzv101 + bzv111) + (bzv001 + bzv111 + bzv011)) * c3 -
        0.5f * ((bzv000 + bzv100 + bzv110) + (bzv000 + bzv110 + bzv010)) * c3 +
        (bxv001 + bxv101 + bxv111) * (zv001 - zv101) * c6 +
        (bxv001 + bxv011 + bxv111) * (zv011 - zv111) * c6 +
        (byv001 + byv101 + byv111) * (zv101 - zv111) * c6 +
        (byv001 + byv011 + byv111) * (zv001 - zv011) * c6 -
        ((bxv000 + bxv100 + bxv110) * (zv000 - zv100) * c6 +
         (bxv000 + bxv010 + bxv110) * (zv010 - zv110) * c6 +
         (byv000 + byv100 + byv110) * (zv100 - zv110) * c6 +
         (byv000 + byv010 + byv110) * (zv000 - zv010) * c6);
    float sbx = bxv000 + bxv001 + bxv010 + bxv011 + bxv100 + bxv101 + bxv110 +
                bxv111;
    float sby = byv000 + byv001 + byv010 + byv011 + byv100 + byv101 + byv110 +
                byv111;
    float sbz = bzv000 + bzv001 + bzv010 + bzv011 + bzv100 + bzv101 + bzv110 +
                bzv111;
    float ave = 0.015625f * (sbx * sbx + sby * sby + sbz * sbz) + 1e-8f;
    float res = flux * flux;
    float flx1 = res * res / ave;
    fs = (double)flx1;
    fq = (double)flx1 * (double)flx1;
  }
  double bs = block_reduce_sum(fs, sh1);
  double bq = block_reduce_sum(fq, sh2);
  if (threadIdx.x == 0) {
    part_sum[blockIdx.x] = bs;
    part_sq[blockIdx.x] = bq;
  }
}

// ---------- stage 3: median filter + sum((x-med)^2) ----------
// R6 int-key structure with SPLIT PARKING for 4 blocks/CU occupancy:
// phase A sorts window elems 0..63, parks ranks 0..31 in LDS (32 KB) and
// carries ranks 32..62 in 31 registers across phase B. Peak liveness
// ~110 regs -> fits the 128-VGPR cap of __launch_bounds__(256,4) without
// AGPR spill; LDS ~38.8 KB -> 4 blocks/CU (prior rounds ran at 2 waves/SIMD
// and were latency-bound: VALUBusy 65% at Occupancy 20%).
// MODE 0: plain field f (dims D,H,W)
// MODE 1: jx on the fly (96,95,95)   MODE 2: jy (95,96,95)   MODE 3: jz (95,95,96)

template <int MODE>
__global__ __launch_bounds__(256, 4) void med_kernel(
    const float* __restrict__ f, const float* __restrict__ bxm,
    const float* __restrict__ bym, const float* __restrict__ bzp, int D, int H,
    int W, double* __restrict__ part) {
  __shared__ int tile[8][6][36];
  __shared__ int Asr[32][256];
  __shared__ double sh[4];
  const int w0 = blockIdx.x * 32;
  const int h0 = blockIdx.y * 2;
  const int d0 = blockIdx.z * 4;
  const int tx = threadIdx.x;  // 0..31
  const int ty = threadIdx.y;  // 0..1
  const int tz = threadIdx.z;  // 0..3
  const int tid = tx + 32 * ty + 64 * tz;

  for (int il = tid; il < 8 * 6 * 36; il += 256) {
    int lw = il % 36;
    int lh = (il / 36) % 6;
    int ld = il / 216;
    int gw = reflect_idx(w0 + lw - 2, W);
    int gh = reflect_idx(h0 + lh - 2, H);
    int gd = reflect_idx(d0 + ld - 2, D);
    float val;
    if (MODE == 0) {
      val = f[(gd * H + gh) * W + gw];
    } else {
      int o = (gd * 96 + gh) * 96 + gw;
      if (MODE == 1) {
        val = 0.5f * ((bzp[o] - bzp[o + 96] + bzp[o + 1] - bzp[o + 97]) -
                      (bym[o] - bym[o + 1] + bym[o + 96] - bym[o + 97]));
      } else if (MODE == 2) {
        val = 0.5f *
              ((bxm[o] - bxm[o + 1] + bxm[o + 9216] - bxm[o + 9217]) -
               (bzp[o] - bzp[o + 9216] + bzp[o + 1] - bzp[o + 9217]));
      } else {
        val = 0.5f *
              ((bym[o] - bym[o + 9216] + bym[o + 96] - bym[o + 9312]) -
               (bxm[o] - bxm[o + 96] + bxm[o + 9216] - bxm[o + 9312]));
      }
    }
    tile[ld][lh][lw] = fkey(val);
  }
  __syncthreads();

  // window element r -> (i,j,l) = (r/25, (r/5)%5, r%5)
#define TW(r) tile[tz + (r) / 25][ty + ((r) / 5) % 5][tx + (r) % 5]

  // ---- phase A: sort first 64 keys; park ranks 0..31 in LDS, carry
  //      ranks 32..62 in registers ----
  int Akeep[31];  // Akeep[j] = A[32+j], j=0..30
  {
    int A[64];
#pragma unroll
    for (int r = 0; r < 64; r++) A[r] = TW(r);
    sortn<64>(A);
#pragma unroll
    for (int i = 0; i < 32; i++) Asr[i][tid] = A[i];
#pragma unroll
    for (int j = 0; j < 31; j++) Akeep[j] = A[32 + j];
  }
  __syncthreads();  // scheduler fence

  // ---- phase B: sort remaining 61 keys + 3 sentinels ----
  int B[64];
#pragma unroll
  for (int r = 64; r < 125; r++) B[r - 64] = TW(r);
  B[61] = KSENT;
  B[62] = KSENT;
  B[63] = KSENT;
  sortn<64>(B);

  int ckey = tile[tz + 2][ty + 2][tx + 2];
#undef TW

  // ---- select rank 62 (0-based) of the 128-union (125 real + 3 sentinels):
  // med = min( B[62], A[62], min_{i=1..62} max(A[i-1], B[62-i]) )
  int m0 = B[62];
  int m1 = Akeep[30];  // A[62]
  int m2 = KSENT;
  int m3 = KSENT;
  // i = 1..32: A[i-1] from LDS ranks 0..31
#pragma unroll
  for (int i = 1; i <= 29; i += 4) {
    m0 = min(m0, max(Asr[i - 1][tid], B[62 - i]));
    m1 = min(m1, max(Asr[i][tid], B[61 - i]));
    m2 = min(m2, max(Asr[i + 1][tid], B[60 - i]));
    m3 = min(m3, max(Asr[i + 2][tid], B[59 - i]));
  }
  // i = 33..60: A[i-1] = Akeep[i-33] (A[32..59])
#pragma unroll
  for (int i = 33; i <= 57; i += 4) {
    m0 = min(m0, max(Akeep[i - 33], B[62 - i]));
    m1 = min(m1, max(Akeep[i - 32], B[61 - i]));
    m2 = min(m2, max(Akeep[i - 31], B[60 - i]));
    m3 = min(m3, max(Akeep[i - 30], B[59 - i]));
  }
  // i = 61, 62: A[60]=Akeep[28], A[61]=Akeep[29]
  m0 = min(m0, max(Akeep[28], B[1]));
  m1 = min(m1, max(Akeep[29], B[0]));
  int mk = min(min(m0, m1), min(m2, m3));

  float dlt = funkey(mk) - funkey(ckey);
  const int w = w0 + tx;
  const int h = h0 + ty;
  const int d = d0 + tz;
  double c = (w < W && h < H && d < D) ? (double)dlt * (double)dlt : 0.0;
  double bs = block_reduce_sum(c, sh);
  if (tid == 0) {
    part[blockIdx.x + 3 * (blockIdx.y + 48 * blockIdx.z)] = bs;
  }
}

// ---------- stage 4: reduce partials, finalize 6 scalars ----------

__global__ __launch_bounds__(256) void finalize_kernel(
    const double* __restrict__ P, float* __restrict__ out) {
  __shared__ double sh[4];
  __shared__ double res[11];
  int tid = threadIdx.x;
  for (int q = 0; q < 11; q++) {
    const double* base =
        (q < 4) ? (P + q * NDIVBLK) : (P + 4 * NDIVBLK + (q - 4) * NMEDBLK);
    int cnt = (q < 4) ? NDIVBLK : NMEDBLK;
    double s = 0.0;
    for (int i = tid; i < cnt; i += 256) s += base[i];
#pragma unroll
    for (int off = 32; off > 0; off >>= 1) s += __shfl_down(s, off, 64);
    if ((tid & 63) == 0) sh[tid >> 6] = s;
    __syncthreads();
    if (tid == 0) res[q] = sh[0] + sh[1] + sh[2] + sh[3];
    __syncthreads();
  }
  if (tid == 0) {
    const double Nd = 95.0 * 95.0 * 95.0;
    const double Nj = 96.0 * 95.0 * 95.0;
    const double Nv = 96.0 * 96.0 * 96.0;
    double mp = res[0] / Nd;
    double mt = res[2] / Nd;
    out[0] = (float)mp;
    out[1] = (float)(res[1] / Nd - mp * mp);
    out[2] = (float)mt;
    out[3] = (float)(res[3] / Nd - mt * mt);
    out[4] = (float)((res[4] + res[5] + res[6]) / Nj);
    out[5] = (float)((res[7] + res[8] + res[9] + res[10]) / Nv);
  }
}

// ---------- launcher ----------

extern "C" void kernel_launch(void* const* d_in, const int* in_sizes, int n_in,
                              void* d_out, int out_size, void* d_ws,
                              size_t ws_size, hipStream_t stream) {
  (void)in_sizes;
  (void)n_in;
  (void)out_size;
  (void)ws_size;
  const float* pred_b = (const float*)d_in[0];
  const float* pred_z = (const float*)d_in[1];
  const float* targets = (const float*)d_in[2];
  float* out = (float*)d_out;

  double* P = (double*)d_ws;                     // 4*NDIVBLK + 7*NMEDBLK doubles
  size_t pdoubles = 4 * NDIVBLK + 7 * NMEDBLK;
  float* bxm = (float*)(P + pdoubles);
  float* bym = bxm + V96;

  const float* bzt = targets + 2 * V96;
  const float* bzp = pred_b + 2 * V96;

  prep_mask_kernel<<<dim3((V96 + 255) / 256), dim3(256), 0, stream>>>(
      pred_b, targets, bxm, bym);

  div_kernel<<<dim3(NDIVBLK), dim3(256), 0, stream>>>(
      pred_b, pred_b + V96, bzt, pred_z, P + 0 * NDIVBLK, P + 1 * NDIVBLK);
  div_kernel<<<dim3(NDIVBLK), dim3(256), 0, stream>>>(
      bxm, bym, bzt, pred_z, P + 2 * NDIVBLK, P + 3 * NDIVBLK);

  double* M = P + 4 * NDIVBLK;
  dim3 blk(32, 2, 4);
  dim3 grd(3, 48, 24);
  med_kernel<1><<<grd, blk, 0, stream>>>(nullptr, bxm, bym, bzp, 96, 95, 95,
                                         M + 0 * NMEDBLK);
  med_kernel<2><<<grd, blk, 0, stream>>>(nullptr, bxm, bym, bzp, 95, 96, 95,
                                         M + 1 * NMEDBLK);
  med_kernel<3><<<grd, blk, 0, stream>>>(nullptr, bxm, bym, bzp, 95, 95, 96,
                                         M + 2 * NMEDBLK);
  med_kernel<0><<<grd, blk, 0, stream>>>(bxm, bxm, bym, bzp, 96, 96, 96,
                                         M + 3 * NMEDBLK);
  med_kernel<0><<<grd, blk, 0, stream>>>(bym, bxm, bym, bzp, 96, 96, 96,
                                         M + 4 * NMEDBLK);
  med_kernel<0><<<grd, blk, 0, stream>>>(pred_b, bxm, bym, bzp, 96, 96, 96,
                                         M + 5 * NMEDBLK);
  med_kernel<0><<<grd, blk, 0, stream>>>(pred_b + V96, bxm, bym, bzp, 96, 96,
                                         96, M + 6 * NMEDBLK);

  finalize_kernel<<<1, 256, 0, stream>>>(P, out);
}

// Round 8
// 584.534 us; speedup vs baseline: 1.2666x; 1.0391x over previous
//
#include <hip/hip_runtime.h>
#include <math.h>

#define V96 (96*96*96)
#define NDIVBLK 3350   // ceil(95^3/256)
#define NMEDBLK 3456   // 3*48*24

#define KSENT 0x7FFFFFFF  // int-key sentinel, > key(+inf)=0x7F800000

// ---------- helpers ----------

__device__ __forceinline__ int reflect_idx(int t, int n) {
  if (t < 0) t = -t;
  if (t >= n) t = 2 * n - 2 - t;
  return t;
}

// Monotone float<->signed-int key transform (involution).
__device__ __forceinline__ int fkey(float f) {
  int b = __float_as_int(f);
  return b ^ ((b >> 31) & 0x7FFFFFFF);
}
__device__ __forceinline__ float funkey(int k) {
  return __int_as_float(k ^ ((k >> 31) & 0x7FFFFFFF));
}

__device__ __forceinline__ void cswap(int& a, int& b) {
  int lo = min(a, b);
  int hi = max(a, b);
  a = lo;
  b = hi;
}

// Batcher odd-even mergesort on v[0..N), N power of 2. Fully unrolled.
template <int N>
__device__ __forceinline__ void sortn(int* v) {
#pragma unroll
  for (int p = 1; p < N; p <<= 1) {
#pragma unroll
    for (int k = p; k >= 1; k >>= 1) {
#pragma unroll
      for (int j = k % p; j <= N - 1 - k; j += 2 * k) {
#pragma unroll
        for (int i = 0; i < k; i++) {
          if (i + j + k <= N - 1) {
            if ((i + j) / (2 * p) == (i + j + k) / (2 * p)) {
              cswap(v[i + j], v[i + j + k]);
            }
          }
        }
      }
    }
  }
}

// 256-thread block: reduce val across block; result valid on tid 0.
__device__ __forceinline__ double block_reduce_sum(double val, double* sh) {
  int tid = threadIdx.x + threadIdx.y * blockDim.x +
            threadIdx.z * blockDim.x * blockDim.y;
  int lane = tid & 63;
  int wv = tid >> 6;
#pragma unroll
  for (int off = 32; off > 0; off >>= 1) val += __shfl_down(val, off, 64);
  if (lane == 0) sh[wv] = val;
  __syncthreads();
  double r = 0.0;
  if (tid == 0) {
#pragma unroll
    for (int i = 0; i < 4; i++) r += sh[i];
  }
  return r;
}

// ---------- stage 1: masked fields ----------

__global__ __launch_bounds__(256) void prep_mask_kernel(
    const float* __restrict__ pred_b, const float* __restrict__ targets,
    float* __restrict__ bxm, float* __restrict__ bym) {
  int i = blockIdx.x * 256 + threadIdx.x;
  if (i >= V96) return;
  float bxp = pred_b[i];
  float byp = pred_b[V96 + i];
  float bxt = targets[i];
  float byt = targets[V96 + i];
  float m = (bxp * bxt + byp * byt > 0.0f) ? 1.0f : -1.0f;
  bxm[i] = bxt * m;
  bym[i] = byt * m;
}

// ---------- stage 2: fused div-c flux reduction (2 x 95^3 cells) ----------
// blockIdx.x < NDIVBLK: predicted fields (pred_bx, pred_by);
// else: masked target fields (bxm, bym). bz, z shared.

__global__ __launch_bounds__(256) void div_fused_kernel(
    const float* __restrict__ pbx, const float* __restrict__ pby,
    const float* __restrict__ bxm, const float* __restrict__ bym,
    const float* __restrict__ bz, const float* __restrict__ z,
    double* __restrict__ P) {
  __shared__ double sh1[4];
  __shared__ double sh2[4];
  const int N = 95 * 95 * 95;
  int which = (blockIdx.x >= NDIVBLK) ? 1 : 0;
  int blk = blockIdx.x - which * NDIVBLK;
  const float* bx = which ? bxm : pbx;
  const float* by = which ? bym : pby;
  int idx = blk * 256 + threadIdx.x;
  double fs = 0.0, fq = 0.0;
  if (idx < N) {
    int w = idx % 95;
    int t = idx / 95;
    int h = t % 95;
    int d = t / 95;
    int o = (d * 96 + h) * 96 + w;
#define LD8(A, p)                                                             \
  float A##000 = p[o], A##001 = p[o + 1], A##010 = p[o + 96],                 \
        A##011 = p[o + 97], A##100 = p[o + 9216], A##101 = p[o + 9217],       \
        A##110 = p[o + 9312], A##111 = p[o + 9313];
    LD8(bxv, bx)
    LD8(byv, by)
    LD8(bzv, bz)
    LD8(zv, z)
#undef LD8
    float az1 = fabsf(zv001 - zv000);
    float az2 = fabsf(zv011 - zv010);
    float az3 = fabsf(zv101 - zv100);
    float az4 = fabsf(zv111 - zv110);
    const float c6 = 1.0f / 6.0f;
    const float c3 = 1.0f / 3.0f;
    float flux =
        0.25f * (bxv100 + bxv110 + bxv101 + bxv111) * 0.5f * (az3 + az4) -
        0.25f * (bxv000 + bxv010 + bxv001 + bxv011) * 0.5f * (az1 + az2) +
        0.25f * (byv010 + byv110 + byv011 + byv111) * 0.5f * (az2 + az4) -
        0.25f * (byv000 + byv100 + byv001 + byv101) * 0.5f * (az1 + az3) +
        0.5f * ((bzv001 + bzv101 + bzv111) + (bzv001 + bzv111 + bzv011)) * c3 -
        0.5f * ((bzv000 + bzv100 + bzv110) + (bzv000 + bzv110 + bzv010)) * c3 +
        (bxv001 + bxv101 + bxv111) * (zv001 - zv101) * c6 +
        (bxv001 + bxv011 + bxv111) * (zv011 - zv111) * c6 +
        (byv001 + byv101 + byv111) * (zv101 - zv111) * c6 +
        (byv001 + byv011 + byv111) * (zv001 - zv011) * c6 -
        ((bxv000 + bxv100 + bxv110) * (zv000 - zv100) * c6 +
         (bxv000 + bxv010 + bxv110) * (zv010 - zv110) * c6 +
         (byv000 + byv100 + byv110) * (zv100 - zv110) * c6 +
         (byv000 + byv010 + byv110) * (zv000 - zv010) * c6);
    float sbx = bxv000 + bxv001 + bxv010 + bxv011 + bxv100 + bxv101 + bxv110 +
                bxv111;
    float sby = byv000 + byv001 + byv010 + byv011 + byv100 + byv101 + byv110 +
                byv111;
    float sbz = bzv000 + bzv001 + bzv010 + bzv011 + bzv100 + bzv101 + bzv110 +
                bzv111;
    float ave = 0.015625f * (sbx * sbx + sby * sby + sbz * sbz) + 1e-8f;
    float res = flux * flux;
    float flx1 = res * res / ave;
    fs = (double)flx1;
    fq = (double)flx1 * (double)flx1;
  }
  double bs = block_reduce_sum(fs, sh1);
  double bq = block_reduce_sum(fq, sh2);
  if (threadIdx.x == 0) {
    P[(which ? 2 : 0) * NDIVBLK + blk] = bs;
    P[(which ? 3 : 1) * NDIVBLK + blk] = bq;
  }
}

// ---------- stage 3: FUSED median filter + sum((x-med)^2), all 7 fields ----
// One dispatch, 7*3456 blocks: field id = blockIdx.z / 24 (wave-uniform).
//   fid 0: jx on the fly (96,95,95)   fid 1: jy (95,96,95)
//   fid 2: jz (95,95,96)              fid 3..6: plain bxm,bym,pbx,pby (96^3)
// R7 per-block structure: (32,2,4) block, tile [8][6][36] int keys,
// split parking (LDS ranks 0..31 / regs ranks 32..62), 4 blocks/CU.

__global__ __launch_bounds__(256, 4) void med_fused_kernel(
    const float* __restrict__ bxm, const float* __restrict__ bym,
    const float* __restrict__ pbx, const float* __restrict__ pby,
    const float* __restrict__ bzp, double* __restrict__ part) {
  __shared__ int tile[8][6][36];
  __shared__ int Asr[32][256];
  __shared__ double sh[4];

  const int gz = blockIdx.z;
  const int fid = gz / 24;        // 0..6, uniform across block
  const int zb = gz - fid * 24;   // 0..23
  const int W = (fid == 0 || fid == 1) ? 95 : 96;
  const int H = (fid == 0 || fid == 2) ? 95 : 96;
  const int D = (fid == 1 || fid == 2) ? 95 : 96;

  const int w0 = blockIdx.x * 32;
  const int h0 = blockIdx.y * 2;
  const int d0 = zb * 4;
  const int tx = threadIdx.x;  // 0..31
  const int ty = threadIdx.y;  // 0..1
  const int tz = threadIdx.z;  // 0..3
  const int tid = tx + 32 * ty + 64 * tz;

  const float* fplain =
      (fid == 3) ? bxm : (fid == 4) ? bym : (fid == 5) ? pbx : pby;

  for (int il = tid; il < 8 * 6 * 36; il += 256) {
    int lw = il % 36;
    int lh = (il / 36) % 6;
    int ld = il / 216;
    int gw = reflect_idx(w0 + lw - 2, W);
    int gh = reflect_idx(h0 + lh - 2, H);
    int gd = reflect_idx(d0 + ld - 2, D);
    float val;
    if (fid >= 3) {
      val = fplain[(gd * H + gh) * W + gw];
    } else {
      int o = (gd * 96 + gh) * 96 + gw;
      if (fid == 0) {
        val = 0.5f * ((bzp[o] - bzp[o + 96] + bzp[o + 1] - bzp[o + 97]) -
                      (bym[o] - bym[o + 1] + bym[o + 96] - bym[o + 97]));
      } else if (fid == 1) {
        val = 0.5f *
              ((bxm[o] - bxm[o + 1] + bxm[o + 9216] - bxm[o + 9217]) -
               (bzp[o] - bzp[o + 9216] + bzp[o + 1] - bzp[o + 9217]));
      } else {
        val = 0.5f *
              ((bym[o] - bym[o + 9216] + bym[o + 96] - bym[o + 9312]) -
               (bxm[o] - bxm[o + 96] + bxm[o + 9216] - bxm[o + 9312]));
      }
    }
    tile[ld][lh][lw] = fkey(val);
  }
  __syncthreads();

  // window element r -> (i,j,l) = (r/25, (r/5)%5, r%5)
#define TW(r) tile[tz + (r) / 25][ty + ((r) / 5) % 5][tx + (r) % 5]

  // ---- phase A: sort first 64 keys; park ranks 0..31 in LDS, carry
  //      ranks 32..62 in registers ----
  int Akeep[31];  // Akeep[j] = A[32+j], j=0..30
  {
    int A[64];
#pragma unroll
    for (int r = 0; r < 64; r++) A[r] = TW(r);
    sortn<64>(A);
#pragma unroll
    for (int i = 0; i < 32; i++) Asr[i][tid] = A[i];
#pragma unroll
    for (int j = 0; j < 31; j++) Akeep[j] = A[32 + j];
  }
  __syncthreads();  // scheduler fence

  // ---- phase B: sort remaining 61 keys + 3 sentinels ----
  int B[64];
#pragma unroll
  for (int r = 64; r < 125; r++) B[r - 64] = TW(r);
  B[61] = KSENT;
  B[62] = KSENT;
  B[63] = KSENT;
  sortn<64>(B);

  int ckey = tile[tz + 2][ty + 2][tx + 2];
#undef TW

  // ---- select rank 62 (0-based) of the 128-union (125 real + 3 sentinels):
  // med = min( B[62], A[62], min_{i=1..62} max(A[i-1], B[62-i]) )
  int m0 = B[62];
  int m1 = Akeep[30];  // A[62]
  int m2 = KSENT;
  int m3 = KSENT;
  // i = 1..32: A[i-1] from LDS ranks 0..31
#pragma unroll
  for (int i = 1; i <= 29; i += 4) {
    m0 = min(m0, max(Asr[i - 1][tid], B[62 - i]));
    m1 = min(m1, max(Asr[i][tid], B[61 - i]));
    m2 = min(m2, max(Asr[i + 1][tid], B[60 - i]));
    m3 = min(m3, max(Asr[i + 2][tid], B[59 - i]));
  }
  // i = 33..60: A[i-1] = Akeep[i-33] (A[32..59])
#pragma unroll
  for (int i = 33; i <= 57; i += 4) {
    m0 = min(m0, max(Akeep[i - 33], B[62 - i]));
    m1 = min(m1, max(Akeep[i - 32], B[61 - i]));
    m2 = min(m2, max(Akeep[i - 31], B[60 - i]));
    m3 = min(m3, max(Akeep[i - 30], B[59 - i]));
  }
  // i = 61, 62: A[60]=Akeep[28], A[61]=Akeep[29]
  m0 = min(m0, max(Akeep[28], B[1]));
  m1 = min(m1, max(Akeep[29], B[0]));
  int mk = min(min(m0, m1), min(m2, m3));

  float dlt = funkey(mk) - funkey(ckey);
  const int w = w0 + tx;
  const int h = h0 + ty;
  const int d = d0 + tz;
  double c = (w < W && h < H && d < D) ? (double)dlt * (double)dlt : 0.0;
  double bs = block_reduce_sum(c, sh);
  if (tid == 0) {
    part[fid * NMEDBLK + blockIdx.x + 3 * (blockIdx.y + 48 * zb)] = bs;
  }
}

// ---------- stage 4: reduce partials, finalize 6 scalars ----------

__global__ __launch_bounds__(256) void finalize_kernel(
    const double* __restrict__ P, float* __restrict__ out) {
  __shared__ double sh[4];
  __shared__ double res[11];
  int tid = threadIdx.x;
  for (int q = 0; q < 11; q++) {
    const double* base =
        (q < 4) ? (P + q * NDIVBLK) : (P + 4 * NDIVBLK + (q - 4) * NMEDBLK);
    int cnt = (q < 4) ? NDIVBLK : NMEDBLK;
    double s = 0.0;
    for (int i = tid; i < cnt; i += 256) s += base[i];
#pragma unroll
    for (int off = 32; off > 0; off >>= 1) s += __shfl_down(s, off, 64);
    if ((tid & 63) == 0) sh[tid >> 6] = s;
    __syncthreads();
    if (tid == 0) res[q] = sh[0] + sh[1] + sh[2] + sh[3];
    __syncthreads();
  }
  if (tid == 0) {
    const double Nd = 95.0 * 95.0 * 95.0;
    const double Nj = 96.0 * 95.0 * 95.0;
    const double Nv = 96.0 * 96.0 * 96.0;
    double mp = res[0] / Nd;
    double mt = res[2] / Nd;
    out[0] = (float)mp;
    out[1] = (float)(res[1] / Nd - mp * mp);
    out[2] = (float)mt;
    out[3] = (float)(res[3] / Nd - mt * mt);
    out[4] = (float)((res[4] + res[5] + res[6]) / Nj);
    out[5] = (float)((res[7] + res[8] + res[9] + res[10]) / Nv);
  }
}

// ---------- launcher ----------

extern "C" void kernel_launch(void* const* d_in, const int* in_sizes, int n_in,
                              void* d_out, int out_size, void* d_ws,
                              size_t ws_size, hipStream_t stream) {
  (void)in_sizes;
  (void)n_in;
  (void)out_size;
  (void)ws_size;
  const float* pred_b = (const float*)d_in[0];
  const float* pred_z = (const float*)d_in[1];
  const float* targets = (const float*)d_in[2];
  float* out = (float*)d_out;

  double* P = (double*)d_ws;                     // 4*NDIVBLK + 7*NMEDBLK doubles
  size_t pdoubles = 4 * NDIVBLK + 7 * NMEDBLK;
  float* bxm = (float*)(P + pdoubles);
  float* bym = bxm + V96;

  const float* bzt = targets + 2 * V96;
  const float* pbx = pred_b;
  const float* pby = pred_b + V96;
  const float* bzp = pred_b + 2 * V96;

  prep_mask_kernel<<<dim3((V96 + 255) / 256), dim3(256), 0, stream>>>(
      pred_b, targets, bxm, bym);

  div_fused_kernel<<<dim3(2 * NDIVBLK), dim3(256), 0, stream>>>(
      pbx, pby, bxm, bym, bzt, pred_z, P);

  double* M = P + 4 * NDIVBLK;
  dim3 blk(32, 2, 4);
  dim3 grd(3, 48, 24 * 7);
  med_fused_kernel<<<grd, blk, 0, stream>>>(bxm, bym, pbx, pby, bzp, M);

  finalize_kernel<<<1, 256, 0, stream>>>(P, out);
}